// Round 7
// baseline (1245.328 us; speedup 1.0000x reference)
//
#include <hip/hip_runtime.h>
#include <hip/hip_cooperative_groups.h>
#include <cmath>

namespace cg = cooperative_groups;

#define NB 8
#define NN 20000
#define ND 128
#define NE_TOT 192000   /* 3 edge sets * 64000 edges, contiguous per batch */
#define NPASS 5

#define RSZ 128                     /* nodes per src-range */
#define NR 157                      /* ceil(NN / RSZ) */
#define CAP 2048                    /* bucket capacity; avg fill 1223 */
#define ECHUNK 8000                 /* edges per bucketing chunk */
#define NCHUNK 24                   /* NE_TOT / ECHUNK, exact */

#define PCH 80                      /* rows per pool tile */
#define PBLK 250                    /* NN / PCH, exact */

#define GRID 1024                   /* 4 blocks/CU guaranteed by launch_bounds */

// globals shared by mega-kernel and fallback path
__device__ float g_w0[NB * NN];
__device__ float g_w1[NB * NN];
__device__ int   g_bcnt[NB][NCHUNK][NR];
__device__ int   g_boff[NB][NCHUNK][NR];
__device__ int   g_cnt[NB * NR];
__device__ int2  g_bucket[(size_t)NB * NR * CAP];   // 20.6 MB
__device__ float g_ppart[(size_t)NB * PBLK * ND];   // 1 MB
__device__ float g_pooled[NB * ND];

// ---------------- cooperative mega-kernel: all phases, one launch ----------------

__global__ void __launch_bounds__(256, 4)
megaK(const float* __restrict__ nodes, const float* __restrict__ ptype,
      const float* __restrict__ w1, const float* __restrict__ b1,
      const float* __restrict__ w2, const float* __restrict__ b2,
      const float* __restrict__ w3, const float* __restrict__ b3,
      const int* __restrict__ edges, float* __restrict__ out) {
    cg::grid_group grid = cg::this_grid();
    const int blk  = blockIdx.x;
    const int t    = threadIdx.x;     // 256
    const int nblk = gridDim.x;
    __shared__ __align__(16) float smf[2312];  // 9248 B, reused per phase

    // ---- phase 0: w0 = 1  +  per-chunk src-range histograms ----
    for (int i = blk * 256 + t; i < NB * NN; i += nblk * 256) g_w0[i] = 1.0f;
    int* hist = (int*)smf;
    for (int u = blk; u < NB * NCHUNK; u += nblk) {
        const int b = u / NCHUNK, c = u % NCHUNK;
        for (int i = t; i < NR; i += 256) hist[i] = 0;
        __syncthreads();
        const int2* ep = (const int2*)edges + (size_t)b * NE_TOT + (size_t)c * ECHUNK;
        for (int i = t; i < ECHUNK; i += 256) atomicAdd(&hist[ep[i].y >> 7], 1);
        __syncthreads();
        for (int i = t; i < NR; i += 256) g_bcnt[b][c][i] = hist[i];
        __syncthreads();
    }
    grid.sync();

    // ---- phase 1: prefix over chunks, one thread per (b, range) ----
    {
        const int tid = blk * 256 + t;
        if (tid < NB * NR) {
            const int b = tid / NR, r = tid % NR;
            int run = 0;
            for (int c = 0; c < NCHUNK; ++c) {
                g_boff[b][c][r] = run;
                run += g_bcnt[b][c][r];
            }
            g_cnt[tid] = run;
        }
    }
    grid.sync();

    // ---- phase 2: distribute edges into capacity-strided buckets ----
    int* cur = (int*)smf;
    for (int u = blk; u < NB * NCHUNK; u += nblk) {
        const int b = u / NCHUNK, c = u % NCHUNK;
        for (int i = t; i < NR; i += 256) cur[i] = g_boff[b][c][i];
        __syncthreads();
        const int2* ep = (const int2*)edges + (size_t)b * NE_TOT + (size_t)c * ECHUNK;
        for (int i = t; i < ECHUNK; i += 256) {
            const int2 e = ep[i];              // e.x = dst, e.y = src
            const int r = e.y >> 7;
            const int pos = atomicAdd(&cur[r], 1);
            if (pos < CAP)
                g_bucket[((size_t)b * NR + r) * CAP + pos] =
                    make_int2(e.x, e.y & (RSZ - 1));
        }
        __syncthreads();
    }
    grid.sync();

    // ---- phases 3..7: NPASS propagation passes (w_next = w + A^T w) ----
    float* acc = smf;
    for (int p = 0; p < NPASS; ++p) {
        const float* __restrict__ w = (p & 1) ? g_w1 : g_w0;
        float* __restrict__ wn      = (p & 1) ? g_w0 : g_w1;
        for (int u = blk; u < NB * NR; u += nblk) {
            const int b = u / NR, r = u % NR;
            __syncthreads();                  // protect acc reuse across units
            if (t < RSZ) acc[t] = 0.0f;
            __syncthreads();
            const int cnt = g_cnt[u];
            const int2* __restrict__ bk = g_bucket + (size_t)u * CAP;
            const float* __restrict__ wb = w + b * NN;
            for (int i = t; i < cnt; i += 256) {
                const int2 e = bk[i];         // x = dst (global), y = src (local)
                unsafeAtomicAdd(&acc[e.y], wb[e.x]);   // ds_add_f32
            }
            __syncthreads();
            const int node = (r << 7) + t;
            if (t < RSZ && node < NN)
                wn[b * NN + node] = wb[node] + acc[t];
        }
        grid.sync();
    }
    // NPASS=5 -> final weights live in g_w1

    // ---- phase 8: weighted pool partials ----
    float4* red = (float4*)smf;
    for (int u = blk; u < NB * PBLK; u += nblk) {
        const int b = u / PBLK, px = u % PBLK;
        const int r0 = px * PCH;
        const int dslot = t & 31, rg = t >> 5;
        const float4* __restrict__ base = (const float4*)(nodes + (size_t)b * NN * ND);
        const float* __restrict__ wb = g_w1 + b * NN;
        float4 a[4];
        a[0] = a[1] = a[2] = a[3] = make_float4(0.f, 0.f, 0.f, 0.f);
#pragma unroll
        for (int k = 0; k < 10; ++k) {        // static a[k&3] indexing
            const int r = r0 + rg + k * 8;
            const float wv = wb[r];
            const float4 v = base[(size_t)r * 32 + dslot];
            a[k & 3].x += wv * v.x; a[k & 3].y += wv * v.y;
            a[k & 3].z += wv * v.z; a[k & 3].w += wv * v.w;
        }
        float4 s4;
        s4.x = (a[0].x + a[1].x) + (a[2].x + a[3].x);
        s4.y = (a[0].y + a[1].y) + (a[2].y + a[3].y);
        s4.z = (a[0].z + a[1].z) + (a[2].z + a[3].z);
        s4.w = (a[0].w + a[1].w) + (a[2].w + a[3].w);
        __syncthreads();                      // protect red reuse across units
        red[t] = s4;
        __syncthreads();
        if (t < 32) {
            float4 s = red[t];
            for (int g = 1; g < 8; ++g) {
                const float4 o = red[g * 32 + t];
                s.x += o.x; s.y += o.y; s.z += o.z; s.w += o.w;
            }
            ((float4*)g_ppart)[((size_t)b * PBLK + px) * 32 + t] = s;
        }
    }
    grid.sync();

    // ---- phase 9: reduce partials -> g_pooled (blocks 0..7) ----
    if (blk < NB) {
        const int b = blk;
        const int d = t & 127, slice = t >> 7;  // 2 slices over 250 partials
        float s = 0.0f;
        for (int p = slice; p < PBLK; p += 2)
            s += g_ppart[((size_t)b * PBLK + p) * ND + d];
        __syncthreads();
        smf[t] = s;
        __syncthreads();
        if (t < 128) g_pooled[b * ND + t] = smf[t] + smf[128 + t];
    }
    grid.sync();

    // ---- phase 10: head (block 0) ----
    if (blk == 0) {
        float* sx  = smf;                 // [NB][ND+1]
        float* h1s = smf + NB * (ND + 1); // [NB][80]
        float* h2s = h1s + NB * 80;       // [NB][80]
        for (int i = t; i < NB * ND; i += 256) {
            const int b = i >> 7, d = i & 127;
            float y = logf(g_pooled[i]);
            if (isnan(y)) y = 0.0f;       // nan -> 0
            y = fmaxf(y, 0.0f);           // relu (folds -inf -> 0)
            sx[b * (ND + 1) + d] = y;
        }
        __syncthreads();
        if (t < NB) {
            float fm = -INFINITY;
            for (int d = 0; d < ND; ++d) {
                const float y = sx[t * (ND + 1) + d];
                if (!isinf(y)) fm = fmaxf(fm, y);
            }
            for (int d = 0; d < ND; ++d)
                if (isinf(sx[t * (ND + 1) + d])) sx[t * (ND + 1) + d] = fm;
            sx[t * (ND + 1) + ND] = ptype[t];
        }
        __syncthreads();
        for (int i = t; i < NB * 80; i += 256) {
            const int b = i / 80, j = i - b * 80;
            float s = b1[j];
            for (int k = 0; k < ND + 1; ++k) s += sx[b * (ND + 1) + k] * w1[k * 80 + j];
            h1s[b * 80 + j] = s > 0.0f ? s : 0.01f * s;
        }
        __syncthreads();
        for (int i = t; i < NB * 80; i += 256) {
            const int b = i / 80, j = i - b * 80;
            float s = b2[j];
            for (int k = 0; k < 80; ++k) s += h1s[b * 80 + k] * w2[k * 80 + j];
            h2s[b * 80 + j] = s > 0.0f ? s : 0.01f * s;
        }
        __syncthreads();
        for (int i = t; i < NB * 10; i += 256) {
            const int b = i / 10, j = i - b * 10;
            float s = b3[j];
            for (int k = 0; k < 80; ++k) s += h2s[b * 80 + k] * w3[k * 10 + j];
            out[b * 10 + j] = s;
        }
    }
}

// ---------------- fallback path (R6 multi-kernel, proven correct) ----------------

__global__ void initK() {
    const int i = blockIdx.x * blockDim.x + threadIdx.x;
    if (i < NB * NN) g_w0[i] = 1.0f;
}

__global__ void countK(const int* __restrict__ edges) {
    __shared__ int hist[NR];
    const int b = blockIdx.x / NCHUNK, c = blockIdx.x % NCHUNK;
    const int t = threadIdx.x;
    for (int i = t; i < NR; i += 256) hist[i] = 0;
    __syncthreads();
    const int2* __restrict__ ep =
        (const int2*)edges + (size_t)b * NE_TOT + (size_t)c * ECHUNK;
    for (int i = t; i < ECHUNK; i += 256) atomicAdd(&hist[ep[i].y >> 7], 1);
    __syncthreads();
    for (int i = t; i < NR; i += 256) g_bcnt[b][c][i] = hist[i];
}

__global__ void scanK() {
    const int b = blockIdx.x, t = threadIdx.x;
    if (t < NR) {
        int run = 0;
        for (int c = 0; c < NCHUNK; ++c) {
            g_boff[b][c][t] = run;
            run += g_bcnt[b][c][t];
        }
        g_cnt[b * NR + t] = run;
    }
}

__global__ void distK(const int* __restrict__ edges) {
    __shared__ int cur[NR];
    const int b = blockIdx.x / NCHUNK, c = blockIdx.x % NCHUNK;
    const int t = threadIdx.x;
    for (int i = t; i < NR; i += 256) cur[i] = g_boff[b][c][i];
    __syncthreads();
    const int2* __restrict__ ep =
        (const int2*)edges + (size_t)b * NE_TOT + (size_t)c * ECHUNK;
    for (int i = t; i < ECHUNK; i += 256) {
        const int2 e = ep[i];
        const int r = e.y >> 7;
        const int pos = atomicAdd(&cur[r], 1);
        if (pos < CAP)
            g_bucket[((size_t)b * NR + r) * CAP + pos] = make_int2(e.x, e.y & (RSZ - 1));
    }
}

__global__ void passK(int sel) {
    __shared__ float acc[RSZ];
    const int b = blockIdx.x / NR, r = blockIdx.x % NR;
    const int t = threadIdx.x;
    const float* __restrict__ w = sel ? g_w1 : g_w0;
    float* __restrict__ wn      = sel ? g_w0 : g_w1;
    if (t < RSZ) acc[t] = 0.0f;
    __syncthreads();
    const int cnt = g_cnt[b * NR + r];
    const int2* __restrict__ bk = g_bucket + ((size_t)b * NR + r) * CAP;
    const float* __restrict__ wb = w + b * NN;
    for (int i = t; i < cnt; i += 256) {
        const int2 e = bk[i];
        unsafeAtomicAdd(&acc[e.y], wb[e.x]);
    }
    __syncthreads();
    const int node = (r << 7) + t;
    if (t < RSZ && node < NN) wn[b * NN + node] = wb[node] + acc[t];
}

__global__ void poolWK(const float* __restrict__ nodes, int wsel) {
    const float* __restrict__ w = wsel ? g_w1 : g_w0;
    const int b  = blockIdx.y;
    const int r0 = blockIdx.x * PCH;
    const int t  = threadIdx.x;
    const int dslot = t & 31, rg = t >> 5;
    const float4* __restrict__ base = (const float4*)(nodes + (size_t)b * NN * ND);
    const float* __restrict__ wb = w + b * NN;
    float4 a[4];
    a[0] = a[1] = a[2] = a[3] = make_float4(0.f, 0.f, 0.f, 0.f);
#pragma unroll
    for (int k = 0; k < 10; ++k) {
        const int r = r0 + rg + k * 8;
        const float wv = wb[r];
        const float4 v = base[(size_t)r * 32 + dslot];
        a[k & 3].x += wv * v.x; a[k & 3].y += wv * v.y;
        a[k & 3].z += wv * v.z; a[k & 3].w += wv * v.w;
    }
    float4 acc;
    acc.x = (a[0].x + a[1].x) + (a[2].x + a[3].x);
    acc.y = (a[0].y + a[1].y) + (a[2].y + a[3].y);
    acc.z = (a[0].z + a[1].z) + (a[2].z + a[3].z);
    acc.w = (a[0].w + a[1].w) + (a[2].w + a[3].w);
    __shared__ float4 red[256];
    red[t] = acc;
    __syncthreads();
    if (t < 32) {
        float4 s = red[t];
        for (int g = 1; g < 8; ++g) {
            const float4 o = red[g * 32 + t];
            s.x += o.x; s.y += o.y; s.z += o.z; s.w += o.w;
        }
        ((float4*)g_ppart)[((size_t)b * PBLK + blockIdx.x) * 32 + t] = s;
    }
}

__global__ void reduceK() {
    const int b = blockIdx.x, t = threadIdx.x;  // 1024 threads
    const int d = t & 127, slice = t >> 7;
    float s = 0.0f;
    for (int p = slice; p < PBLK; p += 8)
        s += g_ppart[((size_t)b * PBLK + p) * ND + d];
    __shared__ float sh[1024];
    sh[t] = s;
    __syncthreads();
    if (t < 128) {
        float v = sh[t];
        for (int g = 1; g < 8; ++g) v += sh[g * 128 + t];
        g_pooled[b * ND + t] = v;
    }
}

__global__ void headK(const float* __restrict__ ptype,
                      const float* __restrict__ w1, const float* __restrict__ b1,
                      const float* __restrict__ w2, const float* __restrict__ b2,
                      const float* __restrict__ w3, const float* __restrict__ b3,
                      float* __restrict__ out) {
    __shared__ float sx[NB][ND + 1];
    __shared__ float sh1[NB][80];
    __shared__ float sh2[NB][80];
    const int t = threadIdx.x;
    for (int i = t; i < NB * ND; i += 256) {
        const int b = i >> 7, d = i & 127;
        float y = logf(g_pooled[i]);
        if (isnan(y)) y = 0.0f;
        y = fmaxf(y, 0.0f);
        sx[b][d] = y;
    }
    __syncthreads();
    if (t < NB) {
        float fm = -INFINITY;
        for (int d = 0; d < ND; ++d) {
            const float y = sx[t][d];
            if (!isinf(y)) fm = fmaxf(fm, y);
        }
        for (int d = 0; d < ND; ++d)
            if (isinf(sx[t][d])) sx[t][d] = fm;
        sx[t][ND] = ptype[t];
    }
    __syncthreads();
    for (int i = t; i < NB * 80; i += 256) {
        const int b = i / 80, j = i - b * 80;
        float s = b1[j];
        for (int k = 0; k < ND + 1; ++k) s += sx[b][k] * w1[k * 80 + j];
        sh1[b][j] = s > 0.0f ? s : 0.01f * s;
    }
    __syncthreads();
    for (int i = t; i < NB * 80; i += 256) {
        const int b = i / 80, j = i - b * 80;
        float s = b2[j];
        for (int k = 0; k < 80; ++k) s += sh1[b][k] * w2[k * 80 + j];
        sh2[b][j] = s > 0.0f ? s : 0.01f * s;
    }
    __syncthreads();
    for (int i = t; i < NB * 10; i += 256) {
        const int b = i / 10, j = i - b * 10;
        float s = b3[j];
        for (int k = 0; k < 80; ++k) s += sh2[b][k] * w3[k * 10 + j];
        out[b * 10 + j] = s;
    }
}

extern "C" void kernel_launch(void* const* d_in, const int* in_sizes, int n_in,
                              void* d_out, int out_size, void* d_ws, size_t ws_size,
                              hipStream_t stream) {
    const float* nodes = (const float*)d_in[0];
    const float* ptype = (const float*)d_in[1];
    const float* w1    = (const float*)d_in[2];
    const float* b1    = (const float*)d_in[3];
    const float* w2    = (const float*)d_in[4];
    const float* b2    = (const float*)d_in[5];
    const float* w3    = (const float*)d_in[6];
    const float* b3    = (const float*)d_in[7];
    const int*   edges = (const int*)d_in[8];
    float* out = (float*)d_out;

    void* args[] = {(void*)&nodes, (void*)&ptype,
                    (void*)&w1, (void*)&b1, (void*)&w2, (void*)&b2,
                    (void*)&w3, (void*)&b3, (void*)&edges, (void*)&out};
    hipError_t err = hipLaunchCooperativeKernel((const void*)megaK, dim3(GRID),
                                                dim3(256), args, 0, stream);
    if (err != hipSuccess) {
        // fallback: proven R6 multi-kernel sequence
        initK<<<(NB * NN + 255) / 256, 256, 0, stream>>>();
        countK<<<NB * NCHUNK, 256, 0, stream>>>(edges);
        scanK<<<NB, 256, 0, stream>>>();
        distK<<<NB * NCHUNK, 256, 0, stream>>>(edges);
        int sel = 0;
        for (int p = 0; p < NPASS; ++p) {
            passK<<<NB * NR, 256, 0, stream>>>(sel);
            sel ^= 1;
        }
        poolWK<<<dim3(PBLK, NB), 256, 0, stream>>>(nodes, sel);
        reduceK<<<NB, 1024, 0, stream>>>();
        headK<<<1, 256, 0, stream>>>(ptype, w1, b1, w2, b2, w3, b3, out);
    }
}

// Round 8
// 132.748 us; speedup vs baseline: 9.3812x; 9.3812x over previous
//
#include <hip/hip_runtime.h>
#include <cmath>

#define NB 8
#define NN 20000
#define ND 128
#define NE_TOT 192000   /* 3 edge sets * 64000 edges, contiguous per batch */

#define RSZ 128                     /* nodes per src-range */
#define NR 157                      /* ceil(NN / RSZ) */
#define CAP 2048                    /* bucket capacity; avg fill 1223 */
#define ECHUNK 8000                 /* edges per bucketing chunk */
#define NCHUNK 24                   /* NE_TOT / ECHUNK, exact */

// weight ping-pong + bucket metadata + buckets + pool partials
__device__ float g_w0[NB * NN];
__device__ float g_w1[NB * NN];
__device__ int   g_bcnt[NB][NCHUNK][NR];
__device__ int   g_cnt[NB * NR];
__device__ int2  g_bucket[(size_t)NB * NR * CAP];   // 20.6 MB
__device__ float g_ppart[(size_t)NB * NR * ND];     // 643 KB

// ---- kernel 1: w0 = 1  +  per-(batch,chunk) src-range histograms ----
__global__ void initCountK(const int* __restrict__ edges) {
    __shared__ int hist[NR];
    const int b = blockIdx.x / NCHUNK, c = blockIdx.x % NCHUNK;
    const int t = threadIdx.x;  // 256

    for (int i = blockIdx.x * 256 + t; i < NB * NN; i += NB * NCHUNK * 256)
        g_w0[i] = 1.0f;

    for (int i = t; i < NR; i += 256) hist[i] = 0;
    __syncthreads();
    const int2* __restrict__ ep =
        (const int2*)edges + (size_t)b * NE_TOT + (size_t)c * ECHUNK;
    for (int i = t; i < ECHUNK; i += 256)
        atomicAdd(&hist[ep[i].y >> 7], 1);
    __syncthreads();
    for (int i = t; i < NR; i += 256) g_bcnt[b][c][i] = hist[i];
}

// ---- kernel 2: distribute edges; each block derives its own prefix offset ----
__global__ void distK(const int* __restrict__ edges) {
    __shared__ int cur[NR];
    const int b = blockIdx.x / NCHUNK, c = blockIdx.x % NCHUNK;
    const int t = threadIdx.x;  // 256
    for (int r = t; r < NR; r += 256) {
        int off = 0;
        for (int cc = 0; cc < c; ++cc) off += g_bcnt[b][cc][r];
        cur[r] = off;
        if (c == NCHUNK - 1) g_cnt[b * NR + r] = off + g_bcnt[b][c][r];
    }
    __syncthreads();
    const int2* __restrict__ ep =
        (const int2*)edges + (size_t)b * NE_TOT + (size_t)c * ECHUNK;
    for (int i = t; i < ECHUNK; i += 256) {
        const int2 e = ep[i];             // e.x = dst, e.y = src
        const int r = e.y >> 7;
        const int pos = atomicAdd(&cur[r], 1);
        if (pos < CAP)                    // impossible for uniform input; guards corruption
            g_bucket[((size_t)b * NR + r) * CAP + pos] = make_int2(e.x, e.y & (RSZ - 1));
    }
}

// ---- kernels 3-6: one propagation pass (w_next = w + A^T w), range-partitioned ----
__global__ void passK(int sel) {
    __shared__ float acc[RSZ];          // 512 B
    const int b = blockIdx.x / NR, r = blockIdx.x % NR;
    const int t = threadIdx.x;          // 256
    const float* __restrict__ w  = sel ? g_w1 : g_w0;
    float* __restrict__ wn       = sel ? g_w0 : g_w1;
    if (t < RSZ) acc[t] = 0.0f;
    __syncthreads();
    const int cnt = g_cnt[b * NR + r];
    const int2* __restrict__ bk = g_bucket + ((size_t)b * NR + r) * CAP;
    const float* __restrict__ wb = w + b * NN;
    for (int i = t; i < cnt; i += 256) {
        const int2 e = bk[i];           // e.x = dst (global), e.y = src (local)
        unsafeAtomicAdd(&acc[e.y], wb[e.x]);   // ds_add_f32
    }
    __syncthreads();
    const int node = (r << 7) + t;
    if (t < RSZ && node < NN)
        wn[b * NN + node] = wb[node] + acc[t];
}

// ---- kernel 7: final pass FUSED with the weighted pool ----
// Block (b,r): compute w5 for its 128-node range (in LDS, never stored), then
// stream those node rows once and emit the 128-float pool partial.
__global__ void pass5poolK(const float* __restrict__ nodes) {
    __shared__ float acc[RSZ];          // A^T w contributions
    __shared__ float w5s[RSZ];          // w5 for this range
    __shared__ __align__(16) float4 red[256];
    const int b = blockIdx.x / NR, r = blockIdx.x % NR;
    const int t = threadIdx.x;          // 256
    const float* __restrict__ wb = g_w0 + b * NN;   // w4 lives in g_w0

    if (t < RSZ) acc[t] = 0.0f;
    __syncthreads();
    const int cnt = g_cnt[b * NR + r];
    const int2* __restrict__ bk = g_bucket + ((size_t)b * NR + r) * CAP;
    for (int i = t; i < cnt; i += 256) {
        const int2 e = bk[i];
        unsafeAtomicAdd(&acc[e.y], wb[e.x]);
    }
    __syncthreads();
    if (t < RSZ) {
        const int node = (r << 7) + t;
        w5s[t] = (node < NN) ? wb[node] + acc[t] : 0.0f;
    }
    __syncthreads();

    // pool this range: part[d] = sum_{n in range} w5[n] * nodes[b][n][d]
    const int dslot = t & 31, rg = t >> 5;
    const float4* __restrict__ base = (const float4*)(nodes + (size_t)b * NN * ND);
    const int nbase = r << 7;
    float4 a[4];
    a[0] = a[1] = a[2] = a[3] = make_float4(0.f, 0.f, 0.f, 0.f);
#pragma unroll
    for (int k = 0; k < 16; ++k) {      // static a[k&3] indexing
        const int nl = rg + (k << 3);
        const int node = nbase + nl;
        if (node < NN) {
            const float wv = w5s[nl];
            const float4 v = base[(size_t)node * 32 + dslot];
            a[k & 3].x += wv * v.x; a[k & 3].y += wv * v.y;
            a[k & 3].z += wv * v.z; a[k & 3].w += wv * v.w;
        }
    }
    float4 s4;
    s4.x = (a[0].x + a[1].x) + (a[2].x + a[3].x);
    s4.y = (a[0].y + a[1].y) + (a[2].y + a[3].y);
    s4.z = (a[0].z + a[1].z) + (a[2].z + a[3].z);
    s4.w = (a[0].w + a[1].w) + (a[2].w + a[3].w);
    red[t] = s4;
    __syncthreads();
    if (t < 32) {
        float4 s = red[t];
        for (int g = 1; g < 8; ++g) {
            const float4 o = red[g * 32 + t];
            s.x += o.x; s.y += o.y; s.z += o.z; s.w += o.w;
        }
        ((float4*)g_ppart)[((size_t)b * NR + r) * 32 + t] = s;
    }
}

// ---- kernel 8: reduce partials + full head, one 1024-thread block ----
__global__ void reduceHeadK(const float* __restrict__ ptype,
                            const float* __restrict__ w1, const float* __restrict__ b1,
                            const float* __restrict__ w2, const float* __restrict__ b2,
                            const float* __restrict__ w3, const float* __restrict__ b3,
                            float* __restrict__ out) {
    __shared__ float sx[NB][ND + 1];
    __shared__ float h1s[NB][80];
    __shared__ float h2s[NB][80];
    const int t = threadIdx.x;          // 1024 == NB * ND
    const int b = t >> 7, d = t & 127;

    float s = 0.0f;
    for (int r = 0; r < NR; ++r)
        s += g_ppart[(((size_t)b * NR + r) << 7) + d];

    float y = logf(s);
    if (isnan(y)) y = 0.0f;             // nan -> 0
    y = fmaxf(y, 0.0f);                 // relu (folds -inf -> 0)
    sx[b][d] = y;
    __syncthreads();

    if (t < NB) {
        float fm = -INFINITY;
        for (int dd = 0; dd < ND; ++dd) {
            const float v = sx[t][dd];
            if (!isinf(v)) fm = fmaxf(fm, v);
        }
        for (int dd = 0; dd < ND; ++dd)
            if (isinf(sx[t][dd])) sx[t][dd] = fm;   // +inf -> finite_max
        sx[t][ND] = ptype[t];
    }
    __syncthreads();

    if (t < NB * 80) {
        const int bb = t / 80, j = t - bb * 80;
        float v = b1[j];
        for (int k = 0; k < ND + 1; ++k) v += sx[bb][k] * w1[k * 80 + j];
        h1s[bb][j] = v > 0.0f ? v : 0.01f * v;      // leaky_relu
    }
    __syncthreads();

    if (t < NB * 80) {
        const int bb = t / 80, j = t - bb * 80;
        float v = b2[j];
        for (int k = 0; k < 80; ++k) v += h1s[bb][k] * w2[k * 80 + j];
        h2s[bb][j] = v > 0.0f ? v : 0.01f * v;
    }
    __syncthreads();

    if (t < NB * 10) {
        const int bb = t / 10, j = t - bb * 10;
        float v = b3[j];
        for (int k = 0; k < 80; ++k) v += h2s[bb][k] * w3[k * 10 + j];
        out[bb * 10 + j] = v;
    }
}

extern "C" void kernel_launch(void* const* d_in, const int* in_sizes, int n_in,
                              void* d_out, int out_size, void* d_ws, size_t ws_size,
                              hipStream_t stream) {
    const float* nodes = (const float*)d_in[0];
    const float* ptype = (const float*)d_in[1];
    const float* w1    = (const float*)d_in[2];
    const float* b1    = (const float*)d_in[3];
    const float* w2    = (const float*)d_in[4];
    const float* b2    = (const float*)d_in[5];
    const float* w3    = (const float*)d_in[6];
    const float* b3    = (const float*)d_in[7];
    const int*   edges = (const int*)d_in[8];
    float* out = (float*)d_out;

    initCountK<<<NB * NCHUNK, 256, 0, stream>>>(edges);
    distK<<<NB * NCHUNK, 256, 0, stream>>>(edges);

    // passes 1..4: w0->w1->w0->w1->w0  (w4 ends in g_w0)
    passK<<<NB * NR, 256, 0, stream>>>(0);
    passK<<<NB * NR, 256, 0, stream>>>(1);
    passK<<<NB * NR, 256, 0, stream>>>(0);
    passK<<<NB * NR, 256, 0, stream>>>(1);

    // pass 5 fused with the pool (w5 never materialized)
    pass5poolK<<<NB * NR, 256, 0, stream>>>(nodes);

    reduceHeadK<<<1, 1024, 0, stream>>>(ptype, w1, b1, w2, b2, w3, b3, out);
}

// Round 9
// 129.665 us; speedup vs baseline: 9.6042x; 1.0238x over previous
//
#include <hip/hip_runtime.h>
#include <cmath>

#define NB 8
#define NN 20000
#define ND 128
#define NE_TOT 192000   /* 3 edge sets * 64000 edges, contiguous per batch */

#define RSZ 128                     /* nodes per src-range */
#define NR 157                      /* ceil(NN / RSZ) */
#define CAP 2048                    /* bucket capacity; avg fill 1223 */
#define ECHUNK 8000                 /* edges per bucketing chunk */
#define NCHUNK 24                   /* NE_TOT / ECHUNK, exact */

#define GR 5                        /* ranges per pass block */
#define NCG 32                      /* range-groups: NCG*GR=160 >= NR */

// weight ping-pong + bucket metadata + buckets + pool partials
__device__ float g_w0[NB * NN];
__device__ float g_w1[NB * NN];
__device__ int   g_bcnt[NB][NCHUNK][NR];
__device__ int   g_cnt[NB * NR];
__device__ int2  g_bucket[(size_t)NB * NR * CAP];   // 20.6 MB
__device__ float g_ppart[NB * NCG * ND];            // 128 KB

// ---- kernel 1: w0 = 1  +  per-(batch,chunk) src-range histograms ----
__global__ void initCountK(const int* __restrict__ edges) {
    __shared__ int hist[NR];
    const int b = blockIdx.x / NCHUNK, c = blockIdx.x % NCHUNK;
    const int t = threadIdx.x;  // 256

    for (int i = blockIdx.x * 256 + t; i < NB * NN; i += NB * NCHUNK * 256)
        g_w0[i] = 1.0f;

    for (int i = t; i < NR; i += 256) hist[i] = 0;
    __syncthreads();
    const int2* __restrict__ ep =
        (const int2*)edges + (size_t)b * NE_TOT + (size_t)c * ECHUNK;
    for (int i = t; i < ECHUNK; i += 256)
        atomicAdd(&hist[ep[i].y >> 7], 1);
    __syncthreads();
    for (int i = t; i < NR; i += 256) g_bcnt[b][c][i] = hist[i];
}

// ---- kernel 2: distribute edges; each block derives its own prefix offset ----
__global__ void distK(const int* __restrict__ edges) {
    __shared__ int cur[NR];
    const int b = blockIdx.x / NCHUNK, c = blockIdx.x % NCHUNK;
    const int t = threadIdx.x;  // 256
    for (int r = t; r < NR; r += 256) {
        int off = 0;
        for (int cc = 0; cc < c; ++cc) off += g_bcnt[b][cc][r];
        cur[r] = off;
        if (c == NCHUNK - 1) g_cnt[b * NR + r] = off + g_bcnt[b][c][r];
    }
    __syncthreads();
    const int2* __restrict__ ep =
        (const int2*)edges + (size_t)b * NE_TOT + (size_t)c * ECHUNK;
    for (int i = t; i < ECHUNK; i += 256) {
        const int2 e = ep[i];             // e.x = dst, e.y = src
        const int r = e.y >> 7;
        const int pos = atomicAdd(&cur[r], 1);
        if (pos < CAP)                    // guards corruption only
            g_bucket[((size_t)b * NR + r) * CAP + pos] = make_int2(e.x, e.y & (RSZ - 1));
    }
}

// ---- kernels 3-6: one pass, full w staged in LDS (gathers -> banked ds_read) ----
__global__ void __launch_bounds__(1024)
passLDSK(int sel) {
    extern __shared__ float w_lds[];      // NN floats = 80 KB (dynamic)
    __shared__ float acc[GR * RSZ];       // 2.5 KB
    const int b  = blockIdx.y;
    const int r0 = blockIdx.x * GR;
    const int gr = min(GR, NR - r0);
    const int t  = threadIdx.x;           // 1024
    const float* __restrict__ w  = sel ? g_w1 : g_w0;
    float* __restrict__ wn       = sel ? g_w0 : g_w1;
    const float* __restrict__ wb = w + b * NN;

    const float4* __restrict__ wb4 = (const float4*)wb;
    for (int i = t; i < NN / 4; i += 1024) ((float4*)w_lds)[i] = wb4[i];
    if (t < GR * RSZ) acc[t] = 0.0f;
    __syncthreads();

    for (int rr = 0; rr < gr; ++rr) {
        const int u = b * NR + r0 + rr;
        const int cnt = g_cnt[u];
        const int2* __restrict__ bk = g_bucket + (size_t)u * CAP;
        float* accr = acc + rr * RSZ;
        for (int i = t; i < cnt; i += 1024) {
            const int2 e = bk[i];         // e.x = dst (global), e.y = src (local)
            unsafeAtomicAdd(&accr[e.y], w_lds[e.x]);   // ds_read + ds_add
        }
    }
    __syncthreads();

    for (int i = t; i < gr * RSZ; i += 1024) {
        const int node = r0 * RSZ + i;
        if (node < NN) wn[b * NN + node] = w_lds[node] + acc[i];
    }
}

// ---- kernel 7: final pass fused with weighted pool of this block's rows ----
__global__ void __launch_bounds__(1024)
pass5poolK(const float* __restrict__ nodes) {
    extern __shared__ float w_lds[];      // 80 KB; reused as reduction buffer
    __shared__ float acc[GR * RSZ];
    __shared__ float w5s[GR * RSZ];
    const int b  = blockIdx.y;
    const int r0 = blockIdx.x * GR;
    const int gr = min(GR, NR - r0);
    const int t  = threadIdx.x;           // 1024
    const float* __restrict__ wb = g_w0 + b * NN;   // w4 lives in g_w0

    const float4* __restrict__ wb4 = (const float4*)wb;
    for (int i = t; i < NN / 4; i += 1024) ((float4*)w_lds)[i] = wb4[i];
    if (t < GR * RSZ) acc[t] = 0.0f;
    __syncthreads();

    for (int rr = 0; rr < gr; ++rr) {
        const int u = b * NR + r0 + rr;
        const int cnt = g_cnt[u];
        const int2* __restrict__ bk = g_bucket + (size_t)u * CAP;
        float* accr = acc + rr * RSZ;
        for (int i = t; i < cnt; i += 1024) {
            const int2 e = bk[i];
            unsafeAtomicAdd(&accr[e.y], w_lds[e.x]);
        }
    }
    __syncthreads();

    if (t < GR * RSZ) {
        const int node = r0 * RSZ + t;
        w5s[t] = (t < gr * RSZ && node < NN) ? w_lds[node] + acc[t] : 0.0f;
    }
    __syncthreads();

    // pool this block's rows: part[d] = sum_rows w5[row] * nodes[b][row][d]
    const int dslot = t & 31, rg = t >> 5;
    const int nbase = r0 * RSZ;
    const int nrows = min(GR * RSZ, NN - nbase);  // 640 (or 160 for last block)
    const float4* __restrict__ base = (const float4*)(nodes + (size_t)b * NN * ND);
    float4 aA = {0.f, 0.f, 0.f, 0.f}, aB = {0.f, 0.f, 0.f, 0.f};
    int row = rg;
    for (; row + 32 < nrows; row += 64) {
        const float wA = w5s[row], wB = w5s[row + 32];
        const float4 vA = base[(size_t)(nbase + row) * 32 + dslot];
        const float4 vB = base[(size_t)(nbase + row + 32) * 32 + dslot];
        aA.x += wA * vA.x; aA.y += wA * vA.y; aA.z += wA * vA.z; aA.w += wA * vA.w;
        aB.x += wB * vB.x; aB.y += wB * vB.y; aB.z += wB * vB.z; aB.w += wB * vB.w;
    }
    if (row < nrows) {
        const float wA = w5s[row];
        const float4 vA = base[(size_t)(nbase + row) * 32 + dslot];
        aA.x += wA * vA.x; aA.y += wA * vA.y; aA.z += wA * vA.z; aA.w += wA * vA.w;
    }
    float4 s4;
    s4.x = aA.x + aB.x; s4.y = aA.y + aB.y; s4.z = aA.z + aB.z; s4.w = aA.w + aB.w;

    __syncthreads();                      // w_lds dead -> reuse as red buffer
    float4* red = (float4*)w_lds;         // red[rg*32 + dslot]
    red[t] = s4;
    __syncthreads();
    if (t < 32) {
        float4 s = red[t];
        for (int g = 1; g < 32; ++g) {
            const float4 o = red[g * 32 + t];
            s.x += o.x; s.y += o.y; s.z += o.z; s.w += o.w;
        }
        ((float4*)g_ppart)[((size_t)b * NCG + blockIdx.x) * 32 + t] = s;
    }
}

// ---- kernel 8: reduce 32 partials per batch + full head, one block ----
__global__ void reduceHeadK(const float* __restrict__ ptype,
                            const float* __restrict__ w1, const float* __restrict__ b1,
                            const float* __restrict__ w2, const float* __restrict__ b2,
                            const float* __restrict__ w3, const float* __restrict__ b3,
                            float* __restrict__ out) {
    __shared__ float sx[NB][ND + 1];
    __shared__ float h1s[NB][80];
    __shared__ float h2s[NB][80];
    const int t = threadIdx.x;          // 1024 == NB * ND
    const int b = t >> 7, d = t & 127;

    float s = 0.0f;
    for (int j = 0; j < NCG; ++j)
        s += g_ppart[(b * NCG + j) * ND + d];

    float y = logf(s);
    if (isnan(y)) y = 0.0f;             // nan -> 0
    y = fmaxf(y, 0.0f);                 // relu (folds -inf -> 0)
    sx[b][d] = y;
    __syncthreads();

    if (t < NB) {
        float fm = -INFINITY;
        for (int dd = 0; dd < ND; ++dd) {
            const float v = sx[t][dd];
            if (!isinf(v)) fm = fmaxf(fm, v);
        }
        for (int dd = 0; dd < ND; ++dd)
            if (isinf(sx[t][dd])) sx[t][dd] = fm;   // +inf -> finite_max
        sx[t][ND] = ptype[t];
    }
    __syncthreads();

    if (t < NB * 80) {
        const int bb = t / 80, j = t - bb * 80;
        float v = b1[j];
        for (int k = 0; k < ND + 1; ++k) v += sx[bb][k] * w1[k * 80 + j];
        h1s[bb][j] = v > 0.0f ? v : 0.01f * v;      // leaky_relu
    }
    __syncthreads();

    if (t < NB * 80) {
        const int bb = t / 80, j = t - bb * 80;
        float v = b2[j];
        for (int k = 0; k < 80; ++k) v += h1s[bb][k] * w2[k * 80 + j];
        h2s[bb][j] = v > 0.0f ? v : 0.01f * v;
    }
    __syncthreads();

    if (t < NB * 10) {
        const int bb = t / 10, j = t - bb * 10;
        float v = b3[j];
        for (int k = 0; k < 80; ++k) v += h2s[bb][k] * w3[k * 10 + j];
        out[bb * 10 + j] = v;
    }
}

extern "C" void kernel_launch(void* const* d_in, const int* in_sizes, int n_in,
                              void* d_out, int out_size, void* d_ws, size_t ws_size,
                              hipStream_t stream) {
    const float* nodes = (const float*)d_in[0];
    const float* ptype = (const float*)d_in[1];
    const float* w1    = (const float*)d_in[2];
    const float* b1    = (const float*)d_in[3];
    const float* w2    = (const float*)d_in[4];
    const float* b2    = (const float*)d_in[5];
    const float* w3    = (const float*)d_in[6];
    const float* b3    = (const float*)d_in[7];
    const int*   edges = (const int*)d_in[8];
    float* out = (float*)d_out;

    initCountK<<<NB * NCHUNK, 256, 0, stream>>>(edges);
    distK<<<NB * NCHUNK, 256, 0, stream>>>(edges);

    // passes 1..4: w0->w1->w0->w1->w0  (w4 ends in g_w0)
    passLDSK<<<dim3(NCG, NB), 1024, NN * sizeof(float), stream>>>(0);
    passLDSK<<<dim3(NCG, NB), 1024, NN * sizeof(float), stream>>>(1);
    passLDSK<<<dim3(NCG, NB), 1024, NN * sizeof(float), stream>>>(0);
    passLDSK<<<dim3(NCG, NB), 1024, NN * sizeof(float), stream>>>(1);

    // pass 5 fused with the pool (w5 never materialized)
    pass5poolK<<<dim3(NCG, NB), 1024, NN * sizeof(float), stream>>>(nodes);

    reduceHeadK<<<1, 1024, 0, stream>>>(ptype, w1, b1, w2, b2, w3, b3, out);
}